// Round 1
// baseline (6093.040 us; speedup 1.0000x reference)
//
#include <hip/hip_runtime.h>
#include <hip/hip_cooperative_groups.h>

namespace cg = cooperative_groups;

#define N_    128
#define T_    64
#define D_    512
#define H_    1280
#define FOURH 5120
#define K3    3072           // h(1280) + attn(1280) + x(512)
#define NSTRIP 80            // 5120 / 64 cols per strip
#define KSPLIT 3
#define KCH   1024           // 3072 / 3
#define NBLOCKS (NSTRIP * KSPLIT)

typedef _Float16 half8 __attribute__((ext_vector_type(8)));
typedef float    f32x4 __attribute__((ext_vector_type(4)));

__device__ __forceinline__ float sigf(float x) { return 1.0f / (1.0f + expf(-x)); }

// ---------------- one-time prep kernels ----------------

// W2t[col][k] = fp16 of [Wh; Wattn; Wx][k][col]  (K-major so B-fragments are contiguous)
__global__ __launch_bounds__(256) void build_w2t(const float* __restrict__ Wh,
                                                 const float* __restrict__ Wa,
                                                 const float* __restrict__ Wx,
                                                 _Float16* __restrict__ W2t) {
  __shared__ float tile[32][33];
  int c0 = blockIdx.x * 32;
  int k0 = blockIdx.y * 32;
  int tx = threadIdx.x, ty = threadIdx.y;
#pragma unroll
  for (int i = 0; i < 4; ++i) {
    int k = k0 + ty + i * 8;
    int col = c0 + tx;
    float v;
    if (k < H_)          v = Wh[(size_t)k * FOURH + col];
    else if (k < 2 * H_) v = Wa[(size_t)(k - H_) * FOURH + col];
    else                 v = Wx[(size_t)(k - 2 * H_) * FOURH + col];
    tile[ty + i * 8][tx] = v;
  }
  __syncthreads();
#pragma unroll
  for (int i = 0; i < 4; ++i) {
    int col = c0 + ty + i * 8;
    int k = k0 + tx;
    W2t[(size_t)col * K3 + k] = (_Float16)tile[tx][ty + i * 8];
  }
}

__global__ __launch_bounds__(256) void cvt_f16(const float* __restrict__ src,
                                               _Float16* __restrict__ dst, int n) {
  for (int i = blockIdx.x * blockDim.x + threadIdx.x; i < n; i += gridDim.x * blockDim.x)
    dst[i] = (_Float16)src[i];
}

// ---------------- attention helper (used by init + sequential kernel) ----------------
// h_sh: current h (f32, LDS). Computes softmax attention, writes attn (fp16) and the
// x-slice for step tnext into the GEMM A-operand row Aop[n][*].
__device__ __forceinline__ void attn_and_x(int n, int tnext, int tid,
                                           const float* __restrict__ h_sh,
                                           float (*red)[16], float* w_sh,
                                           const _Float16* __restrict__ Af16,
                                           const _Float16* __restrict__ x16,
                                           _Float16* __restrict__ Aop) {
  const _Float16* Afn = Af16 + (size_t)n * H_ * 16;
  float s[16];
#pragma unroll
  for (int l = 0; l < 16; ++l) s[l] = 0.f;
  for (int hh = tid; hh < H_; hh += 256) {
    float hv = h_sh[hh];
    const half8* af8 = (const half8*)(Afn + (size_t)hh * 16);
    half8 v0 = af8[0], v1 = af8[1];
#pragma unroll
    for (int l = 0; l < 8; ++l) s[l]     += hv * (float)v0[l];
#pragma unroll
    for (int l = 0; l < 8; ++l) s[8 + l] += hv * (float)v1[l];
  }
#pragma unroll
  for (int l = 0; l < 16; ++l) {
#pragma unroll
    for (int off = 32; off > 0; off >>= 1) s[l] += __shfl_down(s[l], off);
  }
  int lane = tid & 63, wv = tid >> 6;
  if (lane == 0) {
#pragma unroll
    for (int l = 0; l < 16; ++l) red[wv][l] = s[l];
  }
  __syncthreads();
  if (tid == 0) {
    const float scale = 0.02795084972579479f;  // 1/sqrt(1280)
    float sc[16], m = -1e30f;
#pragma unroll
    for (int l = 0; l < 16; ++l) {
      sc[l] = scale * (red[0][l] + red[1][l] + red[2][l] + red[3][l]);
      m = fmaxf(m, sc[l]);
    }
    float ssum = 0.f;
#pragma unroll
    for (int l = 0; l < 16; ++l) { sc[l] = expf(sc[l] - m); ssum += sc[l]; }
    float inv = 1.0f / ssum;
#pragma unroll
    for (int l = 0; l < 16; ++l) w_sh[l] = sc[l] * inv;
  }
  __syncthreads();
  _Float16* Aopn = Aop + (size_t)n * K3;
  for (int hh = tid; hh < H_; hh += 256) {
    const half8* af8 = (const half8*)(Afn + (size_t)hh * 16);
    half8 v0 = af8[0], v1 = af8[1];
    float at = 0.f;
#pragma unroll
    for (int l = 0; l < 8; ++l) at += w_sh[l]     * (float)v0[l];
#pragma unroll
    for (int l = 0; l < 8; ++l) at += w_sh[8 + l] * (float)v1[l];
    Aopn[H_ + hh] = (_Float16)at;
  }
  const _Float16* xs = x16 + ((size_t)n * T_ + tnext) * D_;
  for (int j = tid; j < D_; j += 256) Aopn[2 * H_ + j] = xs[j];
}

// ---------------- init: h0 = mean(Af), c0 = h0, attention for step 0 ----------------
__global__ __launch_bounds__(256) void init_state(const float* __restrict__ A,
                                                  const _Float16* __restrict__ Af16,
                                                  const _Float16* __restrict__ x16,
                                                  float* __restrict__ c,
                                                  _Float16* __restrict__ Aop) {
  __shared__ float h_sh[H_];
  __shared__ float red[4][16];
  __shared__ float w_sh[16];
  int n = blockIdx.x, tid = threadIdx.x;
  const float* Afn = A + (size_t)n * H_ * 16;
  _Float16* Aopn = Aop + (size_t)n * K3;
  for (int hh = tid; hh < H_; hh += 256) {
    const float* af = Afn + (size_t)hh * 16;
    float s = 0.f;
#pragma unroll
    for (int l = 0; l < 16; ++l) s += af[l];
    s *= (1.0f / 16.0f);
    c[(size_t)n * H_ + hh] = s;
    h_sh[hh] = s;
    Aopn[hh] = (_Float16)s;
  }
  __syncthreads();
  attn_and_x(n, 0, tid, h_sh, red, w_sh, Af16, x16, Aop);
}

// ---------------- the sequential recurrence (cooperative) ----------------
__global__ __launch_bounds__(256) void seq_kernel(const _Float16* __restrict__ W2t,
                                                  const _Float16* __restrict__ x16,
                                                  const _Float16* __restrict__ Af16,
                                                  const float* __restrict__ b,
                                                  float* __restrict__ c,
                                                  _Float16* __restrict__ Aop,
                                                  float* __restrict__ P,
                                                  float* __restrict__ out) {
  cg::grid_group grid = cg::this_grid();
  int bid = blockIdx.x, tid = threadIdx.x;
  int strip = bid % NSTRIP, kc = bid / NSTRIP;
  int wv = tid >> 6, lane = tid & 63;
  int lr = lane & 15, lkg = (lane >> 4);  // k-group 0..3, k-offset lkg*8
  __shared__ float h_sh[H_];
  __shared__ float red[4][16];
  __shared__ float w_sh[16];

  for (int t = 0; t < T_; ++t) {
    // ---- phase A: partial GEMM  P[kc] = Aop[:, kc*1024 : +1024] @ W2t-chunk ----
    {
      int r0 = wv * 32, cc0 = strip * 64, k0 = kc * KCH;
      const _Float16* A0 = Aop + (size_t)(r0 + lr) * K3 + k0 + lkg * 8;
      const _Float16* B0 = W2t + (size_t)(cc0 + lr) * K3 + k0 + lkg * 8;
      f32x4 acc[2][4];
#pragma unroll
      for (int ri = 0; ri < 2; ++ri)
#pragma unroll
        for (int ci = 0; ci < 4; ++ci) acc[ri][ci] = (f32x4){0.f, 0.f, 0.f, 0.f};
      for (int kk = 0; kk < KCH; kk += 32) {
        half8 a0 = *(const half8*)(A0 + kk);
        half8 a1 = *(const half8*)(A0 + (size_t)16 * K3 + kk);
#pragma unroll
        for (int ci = 0; ci < 4; ++ci) {
          half8 bf = *(const half8*)(B0 + (size_t)ci * 16 * K3 + kk);
          acc[0][ci] = __builtin_amdgcn_mfma_f32_16x16x32_f16(a0, bf, acc[0][ci], 0, 0, 0);
          acc[1][ci] = __builtin_amdgcn_mfma_f32_16x16x32_f16(a1, bf, acc[1][ci], 0, 0, 0);
        }
      }
      float* Pk = P + (size_t)kc * N_ * FOURH;
#pragma unroll
      for (int ri = 0; ri < 2; ++ri)
#pragma unroll
        for (int ci = 0; ci < 4; ++ci) {
          int col  = cc0 + 16 * ci + lr;
          int rowb = r0 + 16 * ri + lkg * 4;
#pragma unroll
          for (int j = 0; j < 4; ++j)
            Pk[(size_t)(rowb + j) * FOURH + col] = acc[ri][ci][j];
        }
    }
    grid.sync();
    // ---- phase B: gates + output + next-step attention (blocks 0..127) ----
    if (bid < N_) {
      int n = bid;
      const float* P0 = P + (size_t)n * FOURH;
      const float* P1 = P0 + (size_t)N_ * FOURH;
      const float* P2 = P1 + (size_t)N_ * FOURH;
      float* cn_ptr = c + (size_t)n * H_;
      _Float16* Aopn = Aop + (size_t)n * K3;
      for (int hh = tid; hh < H_; hh += 256) {
        float ai  = P0[hh]          + P1[hh]          + P2[hh]          + b[hh];
        float af_ = P0[H_ + hh]     + P1[H_ + hh]     + P2[H_ + hh]     + b[H_ + hh];
        float ao  = P0[2 * H_ + hh] + P1[2 * H_ + hh] + P2[2 * H_ + hh] + b[2 * H_ + hh];
        float ag  = P0[3 * H_ + hh] + P1[3 * H_ + hh] + P2[3 * H_ + hh] + b[3 * H_ + hh];
        float cv = cn_ptr[hh];
        float cnew = sigf(af_) * cv + sigf(ai) * tanhf(ag);
        float hnew = sigf(ao) * tanhf(cnew);
        cn_ptr[hh] = cnew;
        out[((size_t)n * T_ + t) * H_ + hh] = hnew;
        h_sh[hh] = hnew;
        Aopn[hh] = (_Float16)hnew;
      }
      __syncthreads();
      int tn = (t + 1 < T_) ? (t + 1) : (T_ - 1);
      attn_and_x(n, tn, tid, h_sh, red, w_sh, Af16, x16, Aop);
    }
    grid.sync();
  }
}

// ---------------- launch ----------------
extern "C" void kernel_launch(void* const* d_in, const int* in_sizes, int n_in,
                              void* d_out, int out_size, void* d_ws, size_t ws_size,
                              hipStream_t stream) {
  const float* x  = (const float*)d_in[0];
  const float* A  = (const float*)d_in[1];
  const float* Wx = (const float*)d_in[2];
  const float* Wh = (const float*)d_in[3];
  const float* Wa = (const float*)d_in[4];
  const float* b  = (const float*)d_in[5];
  float* out = (float*)d_out;
  char* ws = (char*)d_ws;

  _Float16* W2t  = (_Float16*)(ws);                 // 5120*3072*2  = 31,457,280
  _Float16* x16  = (_Float16*)(ws + 31457280);      // 128*64*512*2 =  8,388,608
  _Float16* Af16 = (_Float16*)(ws + 39845888);      // 128*1280*16*2=  5,242,880
  _Float16* Aop  = (_Float16*)(ws + 45088768);      // 128*3072*2   =    786,432
  float*    c    = (float*)(ws + 45875200);         // 128*1280*4   =    655,360
  float*    P    = (float*)(ws + 46530560);         // 3*128*5120*4 =  7,864,320
                                                    // total ~54.4 MB

  build_w2t<<<dim3(FOURH / 32, K3 / 32), dim3(32, 8), 0, stream>>>(Wh, Wa, Wx, W2t);
  cvt_f16<<<2048, 256, 0, stream>>>(x, x16, N_ * T_ * D_);
  cvt_f16<<<2048, 256, 0, stream>>>(A, Af16, N_ * H_ * 16);
  init_state<<<N_, 256, 0, stream>>>(A, Af16, x16, c, Aop);

  const _Float16* W2t_c = W2t;
  const _Float16* x16_c = x16;
  const _Float16* Af16_c = Af16;
  void* args[8];
  args[0] = (void*)&W2t_c;
  args[1] = (void*)&x16_c;
  args[2] = (void*)&Af16_c;
  args[3] = (void*)&b;
  args[4] = (void*)&c;
  args[5] = (void*)&Aop;
  args[6] = (void*)&P;
  args[7] = (void*)&out;
  hipLaunchCooperativeKernel(seq_kernel, dim3(NBLOCKS), dim3(256), args, 0, stream);
}